// Round 2
// 10698.760 us; speedup vs baseline: 1.1456x; 1.1456x over previous
//
#include <hip/hip_runtime.h>
#include <cstdint>
#include <cstddef>

// ============================================================================
// Persistent fused 2-layer LSTM + FC for MI355X (gfx950) — Round 7b:
// coherence-fabric decongestion (R7 + compile fix: __hip_atomic_fence ->
// __builtin_amdgcn_fence). R6 post-mortem: all pipes idle (Mfma 1.9%,
// VALU 1.8%, HBM 0.8%) at 24.4us/round vs ~8us modeled => latency/contention
// bound on the grid-sync + h-state round trip. Three fixes, one theory:
//   1. Aggregator barrier: blocks post flags[bk]; ONLY block 0 sweeps all 256
//      flags and publishes a single generation word; every block polls ONE
//      dword with ONE lane (was: 256 blocks x 64 lanes x 4 sc1 loads spinning
//      on 4-8 LLC lines — a fabric storm concurrent with the critical path).
//   2. Staged h reads become PLAIN cacheable 16B loads. The barrier's acquire
//      fence (buffer_inv; same cost the old acquire load already paid) makes
//      this safe per the release/acquire chain (cooperative grid.sync
//      contract). Per-XCD L2 now serves 31 of 32 blocks: LLC broadcast
//      traffic 32MB -> ~1-4MB per round.
//   3. Finalize lanes remapped (lane = b*2+p, units {2p,2p+1}): h written as
//      packed u32 agent stores — 64x4B mergeable to 8B segments instead of
//      128 scattered 2B partial-line writes.
// MFMA structure, LDS layout, zone reduction, FC path unchanged from R6.
// ============================================================================

#define NBLK 256
#define NTHR 512

typedef _Float16 f16;
typedef _Float16 f16x8 __attribute__((ext_vector_type(8)));
typedef float f32x4 __attribute__((ext_vector_type(4)));
typedef unsigned long long u64;

namespace {
constexpr int kB = 32, kT = 512, kI = 256, kH = 1024, kO = 512, kTR = 500;
constexpr int kRounds = 502;
// workspace layout (bytes)
constexpr size_t kH1Off = 4096;                      // flags in [0,4096)
constexpr size_t kH1Bytes = 503ull * kB * kH * 2;    // h1 f16 [503][32][1024]
constexpr size_t kH2Off = kH1Off + kH1Bytes;         // h2 f16 [502][32][1024]
// LDS: h1 stage [32][1032] f16 | h2 stage same | zone 6*16*17 f32
constexpr int kStageRow = 1032;                      // f16 per b-row (pad 8)
constexpr int kH2Lds = kB * kStageRow;               // f16 index 33024
constexpr int kZoneBytes = 6 * 16 * 17 * 4;          // 6528
constexpr int kLdsBytes = 2 * kB * kStageRow * 2 + kZoneBytes;  // 138624
constexpr int kGen = 512;                            // generation word idx
}

// ---------------------------------------------------------------------------
// Aggregator grid barrier. Producers release flags[bk]; block 0 (the only
// sweeper) acquires them, publishes gen; consumers poll gen with one lane,
// then acquire-fence (emits buffer_inv => plain cached loads after the
// barrier see all pre-release stores, incl. cross-XCD).
__device__ __forceinline__ void grid_barrier(unsigned* flags, unsigned step) {
  __syncthreads();
  const int tid = threadIdx.x;
  if (tid == 0)
    __hip_atomic_store(&flags[blockIdx.x], step, __ATOMIC_RELEASE,
                       __HIP_MEMORY_SCOPE_AGENT);
  if (blockIdx.x == 0 && tid < 64) {
    const int l4 = tid << 2;
    bool done;
    do {
      unsigned ok = 1u;
#pragma unroll
      for (int k = 0; k < 4; ++k)
        ok &= (unsigned)(__hip_atomic_load(&flags[l4 + k], __ATOMIC_RELAXED,
                                           __HIP_MEMORY_SCOPE_AGENT) >= step);
      done = __all((int)ok);
      if (!done) __builtin_amdgcn_s_sleep(1);
    } while (!done);
    if (tid == 0) {
      __builtin_amdgcn_fence(__ATOMIC_ACQUIRE, "agent");
      __hip_atomic_store(&flags[kGen], step, __ATOMIC_RELEASE,
                         __HIP_MEMORY_SCOPE_AGENT);
    }
  }
  if (tid == 0) {
    while (__hip_atomic_load(&flags[kGen], __ATOMIC_RELAXED,
                             __HIP_MEMORY_SCOPE_AGENT) < step)
      __builtin_amdgcn_s_sleep(1);
    __builtin_amdgcn_fence(__ATOMIC_ACQUIRE, "agent");
  }
  __syncthreads();
}

__device__ __forceinline__ float sigmoid_f(float x) {
  return __builtin_amdgcn_rcpf(1.f + __expf(-x));
}
__device__ __forceinline__ float tanh_f(float x) {
  return 1.f - 2.f * __builtin_amdgcn_rcpf(1.f + __expf(2.f * x));
}
__device__ __forceinline__ f16x8 load8(const float* p) {
  f16x8 r;
#pragma unroll
  for (int j = 0; j < 8; ++j) r[j] = (f16)p[j];
  return r;
}

__global__ void __launch_bounds__(256, 1) lstm_init_kernel(char* ws) {
  const int idx = blockIdx.x * 256 + threadIdx.x;     // 32768 threads
  unsigned* flags = (unsigned*)ws;
  if (idx < 1024) flags[idx] = 0u;
  if (idx < 16384) {                                  // zero slot 0 (32768 f16)
    ((unsigned*)(ws + kH1Off))[idx] = 0u;
    ((unsigned*)(ws + kH2Off))[idx] = 0u;
  }
}

__global__ void __launch_bounds__(NTHR, 1) __attribute__((amdgpu_waves_per_eu(2)))
lstm_mfma_kernel(const float* __restrict__ x,
                 const float* __restrict__ Wih0, const float* __restrict__ Whh0,
                 const float* __restrict__ bih0, const float* __restrict__ bhh0,
                 const float* __restrict__ Wih1, const float* __restrict__ Whh1,
                 const float* __restrict__ bih1, const float* __restrict__ bhh1,
                 const float* __restrict__ Wfc, const float* __restrict__ bfc,
                 float* __restrict__ out, char* __restrict__ ws) {
  const int tid = threadIdx.x;
  const int bk = blockIdx.x;
  const int w = tid >> 6;                 // wave 0..7
  const int lane = tid & 63;
  const int m = lane & 15;                // A row / B col / D col
  const int kg = lane >> 4;               // k-group 0..3 (k = kg*8 + j)
  const int q = m >> 2, g = m & 3;        // A-row -> (unit-in-tile, gate)
  const int U0 = bk * 4;                  // owned unit base (both layers)

  unsigned* flags = (unsigned*)ws;
  f16* h1g = (f16*)(ws + kH1Off);         // [503][32][1024]
  f16* h2g = (f16*)(ws + kH2Off);         // [502][32][1024]
  extern __shared__ f16 lds[];
  float* zone = (float*)((char*)lds + 2 * kB * kStageRow * 2);  // 6*272 f32

  // ---- one-time A-fragment (weight) preload, f16 in VGPRs ----
  // A[m][k]: m = lane&15, k = kc*32 + (lane>>4)*8 + j   [m120 layout]
  f16x8 wL0[5], wL1[8], wFC[4];
#pragma unroll
  for (int i = 0; i < 4; ++i)             // L0 rec chunks (K 0..1023 of Whh0)
    wL0[i] = load8(Whh0 + (size_t)(g * kH + U0 + q) * kH + (w + 8 * i) * 32 + kg * 8);
  wL0[4] = load8(Wih0 + (size_t)(g * kH + U0 + q) * kI + w * 32 + kg * 8);
#pragma unroll
  for (int i = 0; i < 4; ++i)             // L1 input chunks (Wih1, K=h1)
    wL1[i] = load8(Wih1 + (size_t)(g * kH + U0 + q) * kH + (w + 8 * i) * 32 + kg * 8);
#pragma unroll
  for (int i = 4; i < 8; ++i)             // L1 rec chunks (Whh1, K=h2)
    wL1[i] = load8(Whh1 + (size_t)(g * kH + U0 + q) * kH + (w + 8 * (i - 4)) * 32 + kg * 8);
#pragma unroll
  for (int i = 0; i < 4; ++i) {           // FC rows: only m<2 valid (o=bk*2+m)
    f16x8 v = load8(Wfc + (size_t)(bk * 2 + (m < 2 ? m : 0)) * kH + (w + 8 * i) * 32 + kg * 8);
    if (m >= 2) {
#pragma unroll
      for (int j = 0; j < 8; ++j) v[j] = (f16)0.f;
    }
    wFC[i] = v;
  }
  // biases for finalize mapping: lane (b = lane>>1, p = lane&1, units 2p+s)
  const int pb = lane & 1;
  float biasL0[2][4], biasL1[2][4];
#pragma unroll
  for (int s = 0; s < 2; ++s) {
#pragma unroll
    for (int j = 0; j < 4; ++j) {
      const int uq = U0 + 2 * pb + s;
      biasL0[s][j] = bih0[j * kH + uq] + bhh0[j * kH + uq];
      biasL1[s][j] = bih1[j * kH + uq] + bhh1[j * kH + uq];
    }
  }
  const float bfc0 = bfc[bk * 2], bfc1 = bfc[bk * 2 + 1];
  float cL0[2] = {0.f, 0.f}, cL1[2] = {0.f, 0.f};  // c-state per (unit 2p+s)

  for (int r = 1; r <= kRounds; ++r) {
    // ---- zero reduction zone (overlaps staging load latency)
    for (int i = tid; i < 6 * 272; i += NTHR) zone[i] = 0.f;
    // ---- stage h1[r-1], h2[max(r-2,0)]: PLAIN cached 16B loads (L2-shared
    //      within XCD; freshness guaranteed by barrier acquire fence).
    {
      const f16x8* s1 = (const f16x8*)(h1g + (size_t)(r - 1) * (kB * kH));
      const f16x8* s2 = (const f16x8*)(h2g + (size_t)(r >= 2 ? r - 2 : 0) * (kB * kH));
#pragma unroll
      for (int ii = 0; ii < 8; ii += 4) {
        f16x8 a[4], b[4];
#pragma unroll
        for (int k2 = 0; k2 < 4; ++k2) {
          const int idx = (ii + k2) * NTHR + tid;
          a[k2] = s1[idx];
          b[k2] = s2[idx];
        }
#pragma unroll
        for (int k2 = 0; k2 < 4; ++k2) {
          const int idx = (ii + k2) * NTHR + tid;
          const int bb = idx >> 7, uu = (idx & 127) * 8;   // [b][u] layout
          *(f16x8*)(lds + bb * kStageRow + uu) = a[k2];
          *(f16x8*)(lds + kH2Lds + bb * kStageRow + uu) = b[k2];
        }
      }
    }
    __syncthreads();

    // ================= MFMA sections (K chunks w, w+8, ...) =================
    // ---- L0: D = Whh0 @ h1[r-1]  +  Wih0 @ x[r-1]
    {
      f32x4 a0 = {0.f, 0.f, 0.f, 0.f}, a1 = {0.f, 0.f, 0.f, 0.f};
#pragma unroll
      for (int i = 0; i < 4; ++i) {
        const int k = (w + 8 * i) * 32 + kg * 8;
        f16x8 b0 = *(const f16x8*)(lds + m * kStageRow + k);
        f16x8 b1 = *(const f16x8*)(lds + (16 + m) * kStageRow + k);
        a0 = __builtin_amdgcn_mfma_f32_16x16x32_f16(wL0[i], b0, a0, 0, 0, 0);
        a1 = __builtin_amdgcn_mfma_f32_16x16x32_f16(wL0[i], b1, a1, 0, 0, 0);
      }
      {  // x chunk: K' = w*32 .. w*32+31 of I=256
        const int kp = w * 32 + kg * 8;
        const float* xp0 = x + ((size_t)m * kT + (r - 1)) * kI + kp;
        f16x8 b0 = load8(xp0);
        f16x8 b1 = load8(xp0 + (size_t)16 * kT * kI);
        a0 = __builtin_amdgcn_mfma_f32_16x16x32_f16(wL0[4], b0, a0, 0, 0, 0);
        a1 = __builtin_amdgcn_mfma_f32_16x16x32_f16(wL0[4], b1, a1, 0, 0, 0);
      }
#pragma unroll
      for (int j = 0; j < 4; ++j) {
        atomicAdd(&zone[0 * 272 + (kg * 4 + j) * 17 + m], a0[j]);
        atomicAdd(&zone[1 * 272 + (kg * 4 + j) * 17 + m], a1[j]);
      }
    }
    // ---- L1: D = Wih1 @ h1[r-1]  +  Whh1 @ h2[r-2]
    {
      f32x4 a0 = {0.f, 0.f, 0.f, 0.f}, a1 = {0.f, 0.f, 0.f, 0.f};
#pragma unroll
      for (int i = 0; i < 4; ++i) {
        const int k = (w + 8 * i) * 32 + kg * 8;
        f16x8 b0 = *(const f16x8*)(lds + m * kStageRow + k);
        f16x8 b1 = *(const f16x8*)(lds + (16 + m) * kStageRow + k);
        a0 = __builtin_amdgcn_mfma_f32_16x16x32_f16(wL1[i], b0, a0, 0, 0, 0);
        a1 = __builtin_amdgcn_mfma_f32_16x16x32_f16(wL1[i], b1, a1, 0, 0, 0);
      }
#pragma unroll
      for (int i = 4; i < 8; ++i) {
        const int k = (w + 8 * (i - 4)) * 32 + kg * 8;
        f16x8 b0 = *(const f16x8*)(lds + kH2Lds + m * kStageRow + k);
        f16x8 b1 = *(const f16x8*)(lds + kH2Lds + (16 + m) * kStageRow + k);
        a0 = __builtin_amdgcn_mfma_f32_16x16x32_f16(wL1[i], b0, a0, 0, 0, 0);
        a1 = __builtin_amdgcn_mfma_f32_16x16x32_f16(wL1[i], b1, a1, 0, 0, 0);
      }
#pragma unroll
      for (int j = 0; j < 4; ++j) {
        atomicAdd(&zone[2 * 272 + (kg * 4 + j) * 17 + m], a0[j]);
        atomicAdd(&zone[3 * 272 + (kg * 4 + j) * 17 + m], a1[j]);
      }
    }
    // ---- FC: D = Wfc @ h2[r-2]   (rows 0,1 valid; rest zero weights)
    {
      f32x4 a0 = {0.f, 0.f, 0.f, 0.f}, a1 = {0.f, 0.f, 0.f, 0.f};
#pragma unroll
      for (int i = 0; i < 4; ++i) {
        const int k = (w + 8 * i) * 32 + kg * 8;
        f16x8 b0 = *(const f16x8*)(lds + kH2Lds + m * kStageRow + k);
        f16x8 b1 = *(const f16x8*)(lds + kH2Lds + (16 + m) * kStageRow + k);
        a0 = __builtin_amdgcn_mfma_f32_16x16x32_f16(wFC[i], b0, a0, 0, 0, 0);
        a1 = __builtin_amdgcn_mfma_f32_16x16x32_f16(wFC[i], b1, a1, 0, 0, 0);
      }
#pragma unroll
      for (int j = 0; j < 2; ++j) {       // only rows 0,1 needed
        if (kg == 0) {
          atomicAdd(&zone[4 * 272 + j * 17 + m], a0[j]);
          atomicAdd(&zone[5 * 272 + j * 17 + m], a1[j]);
        }
      }
    }
    __syncthreads();

    // ================= finalize (waves 0/1/2) =================
    // lane = b*2+p: batch b = lane>>1, unit pair {2p, 2p+1}. Packs both units
    // into one u32 agent store (coalesced vs 2B scatter).
    if (w == 0) {                          // L0 gate math -> h1[r]
      const int b = lane >> 1, p = lane & 1;
      const float* z = zone + (b >> 4) * 272;
      const int col = b & 15;
      f16 hv[2];
#pragma unroll
      for (int s = 0; s < 2; ++s) {
        const int q4 = (2 * p + s) * 4;
        const float pi = z[(q4 + 0) * 17 + col] + biasL0[s][0];
        const float pf = z[(q4 + 1) * 17 + col] + biasL0[s][1];
        const float pg = z[(q4 + 2) * 17 + col] + biasL0[s][2];
        const float po = z[(q4 + 3) * 17 + col] + biasL0[s][3];
        float cc = cL0[s];
        cc = sigmoid_f(pf) * cc + sigmoid_f(pi) * tanh_f(pg);
        cL0[s] = cc;
        hv[s] = (f16)(sigmoid_f(po) * tanh_f(cc));
      }
      unsigned pk;
      __builtin_memcpy(&pk, hv, 4);
      __hip_atomic_store(
          (unsigned*)(h1g + (size_t)r * (kB * kH) + (size_t)b * kH + U0 + 2 * p),
          pk, __ATOMIC_RELAXED, __HIP_MEMORY_SCOPE_AGENT);
    } else if (w == 1 && r >= 2) {         // L1 gate math -> h2[r-1]
      const int b = lane >> 1, p = lane & 1;
      const float* z = zone + (2 + (b >> 4)) * 272;
      const int col = b & 15;
      f16 hv[2];
#pragma unroll
      for (int s = 0; s < 2; ++s) {
        const int q4 = (2 * p + s) * 4;
        const float pi = z[(q4 + 0) * 17 + col] + biasL1[s][0];
        const float pf = z[(q4 + 1) * 17 + col] + biasL1[s][1];
        const float pg = z[(q4 + 2) * 17 + col] + biasL1[s][2];
        const float po = z[(q4 + 3) * 17 + col] + biasL1[s][3];
        float cc = cL1[s];
        cc = sigmoid_f(pf) * cc + sigmoid_f(pi) * tanh_f(pg);
        cL1[s] = cc;
        hv[s] = (f16)(sigmoid_f(po) * tanh_f(cc));
      }
      unsigned pk;
      __builtin_memcpy(&pk, hv, 4);
      __hip_atomic_store(
          (unsigned*)(h2g + (size_t)(r - 1) * (kB * kH) + (size_t)b * kH + U0 + 2 * p),
          pk, __ATOMIC_RELAXED, __HIP_MEMORY_SCOPE_AGENT);
    } else if (w == 2 && r >= 3 && lane < 32) {  // FC -> out[:, r-3, :]
      const int b = lane;
      const float* z = zone + (4 + (lane >> 4)) * 272;
      const int c = lane & 15;
      float2 v;
      v.x = z[0 * 17 + c] + bfc0;
      v.y = z[1 * 17 + c] + bfc1;
      *(float2*)(out + ((size_t)b * kTR + (r - 3)) * kO + bk * 2) = v;
    }
    grid_barrier(flags, (unsigned)r);
  }
}

extern "C" void kernel_launch(void* const* d_in, const int* in_sizes, int n_in,
                              void* d_out, int out_size, void* d_ws,
                              size_t ws_size, hipStream_t stream) {
  const float* x    = (const float*)d_in[0];
  const float* Wih0 = (const float*)d_in[1];
  const float* Whh0 = (const float*)d_in[2];
  const float* bih0 = (const float*)d_in[3];
  const float* bhh0 = (const float*)d_in[4];
  const float* Wih1 = (const float*)d_in[5];
  const float* Whh1 = (const float*)d_in[6];
  const float* bih1 = (const float*)d_in[7];
  const float* bhh1 = (const float*)d_in[8];
  const float* Wfc  = (const float*)d_in[9];
  const float* bfc  = (const float*)d_in[10];
  float* out = (float*)d_out;
  char* ws   = (char*)d_ws;

  (void)hipFuncSetAttribute((const void*)lstm_mfma_kernel,
                            hipFuncAttributeMaxDynamicSharedMemorySize,
                            kLdsBytes);

  hipLaunchKernelGGL(lstm_init_kernel, dim3(128), dim3(256), 0, stream, ws);
  hipLaunchKernelGGL(lstm_mfma_kernel, dim3(NBLK), dim3(NTHR), kLdsBytes,
                     stream, x, Wih0, Whh0, bih0, bhh0, Wih1, Whh1, bih1,
                     bhh1, Wfc, bfc, out, ws);
}